// Round 6
// baseline (274.043 us; speedup 1.0000x reference)
//
#include <hip/hip_runtime.h>

// LSTM B=4096, S=512, INPUT=1, HIDDEN=20 + linear head.
// R7: R6b (2048 single-wave blocks x 2 chains, 2 waves/SIMD balanced) with
// the h-broadcast moved OFF the LDS round-trip.  R6b post-mortem: wall 886
// cyc/step/SIMD = 647 issue (VALUBusy 73%) + ~240 serial stall; the stall is
// the in-chain ds_write(h) -> lgkm wait -> ds_read_b128 (~120cyc) round trip.
// Now h stays in registers: lane j owns h_j; per step:
//   cvt f16 -> ds_swizzle(xor1) neighbor -> pack (h_2m,h_2m+1) in even lanes
//   -> 10x ds_bpermute_b32 (precomputed indices) broadcasts all 10 packed
//   words to every lane in ONE crossbar trip (~35cyc vs ~150-200).
// The ds_write_b16 of h remains (head needs rows per chunk) but is out of
// the dependent chain.  Dummy-group writes now use j (0..23, spread across
// the 24-half row) instead of clamped ju -> kills same-address write
// conflicts (R6b's 2.3M SQ_LDS_BANK_CONFLICT).
// Kept: fused-reciprocal activations (5 exp2 + 2 rcp), split 5+5 dot chains,
// v_dot2_f32_f16, deferred head per 16-step chunk.
// Parity check: group bases 0/20/40 are even and xor-1 never crosses the
// 32-lane swizzle boundary (31<->30, 32<->33), so even lanes hold correct
// pairs and bpermute targets (base+2m) are always even lanes.

#define BATCH 4096
#define SLEN  512
#define H     20
#define CHUNK 16
#define LOG2E 1.44269504088896340736f
#define GSTRIDE 200   // words per group LDS region (16 rows * 12 + 8 pad)
#define RSTRIDE 12    // words per h row (10 half2 used + 2 pad)

typedef _Float16 h2 __attribute__((ext_vector_type(2)));

__device__ __forceinline__ float fexp2(float x) { return __builtin_amdgcn_exp2f(x); }
__device__ __forceinline__ float frcp(float x)  { return __builtin_amdgcn_rcpf(x); }
__device__ __forceinline__ h2 bch2(unsigned int u) { return __builtin_bit_cast(h2, u); }

__global__ __launch_bounds__(64, 2) void lstm_fused(
    const float* __restrict__ x,      // [B, S, 1]
    const float* __restrict__ W_ih,   // [80, 1]
    const float* __restrict__ W_hh,   // [80, 20]
    const float* __restrict__ b_ih,   // [80]
    const float* __restrict__ b_hh,   // [80]
    const float* __restrict__ W_lin,  // [1, 20]
    const float* __restrict__ b_lin,  // [1]
    float* __restrict__ out)          // [B, S, 1]
{
    __shared__ __align__(16) unsigned int hw[3 * GSTRIDE];  // h rows for head (grp2 = scratch)
    __shared__ float xbuf[3][CHUNK];
    _Float16* hh = (_Float16*)hw;

    const int lane = threadIdx.x;       // 0..63
    int grp = lane / H;                 // 0,1 real chains
    if (grp > 2) grp = 2;               // lanes 40..63 all dummy group 2
    const int j    = lane - grp * H;    // 0..19 real; 0..23 for dummy grp
    const bool valid = (grp < 2);
    const long b  = (long)blockIdx.x * 2 + grp;   // 2048*2 = 4096 exact
    const long bc = valid ? b : 0;                // dummies chew on chain 0's x

    const float s1 = -LOG2E;          // sigmoid pre-scale
    const float s2 = -2.0f * LOG2E;   // tanh pre-scale

    // ---- per-lane weights: 4 gate rows x 10 half2 (40 VGPRs), pre-scaled ----
    const int ju = (j < H) ? j : 0;   // clamp dummy lanes' row index (weights only)
    h2 w2[4][10];
    float bb[4], xw[4];
#pragma unroll
    for (int g = 0; g < 4; ++g) {
        const int row = g * H + ju;
        const float sc = (g == 2) ? s2 : s1;   // torch gate order i,f,g,o
#pragma unroll
        for (int k = 0; k < 10; ++k) {
            h2 t;
            t.x = (_Float16)(sc * W_hh[row * H + 2 * k]);
            t.y = (_Float16)(sc * W_hh[row * H + 2 * k + 1]);
            w2[g][k] = t;
        }
        bb[g] = sc * (b_ih[row] + b_hh[row]);
        xw[g] = sc * W_ih[row];
    }
    h2 wl2[10];
#pragma unroll
    for (int k = 0; k < 10; ++k) {
        h2 t;
        t.x = (_Float16)W_lin[2 * k];
        t.y = (_Float16)W_lin[2 * k + 1];
        wl2[k] = t;
    }
    const float blin = b_lin[0];

    // ---- bpermute byte-indices: word m comes from lane grp*20 + 2m ----
    int idx[10];
#pragma unroll
    for (int m = 0; m < 10; ++m) idx[m] = (grp * H + 2 * m) * 4;

    const float* xb = x + bc * SLEN;
    float*       ob = out + bc * SLEN;

    const int gbase = grp * GSTRIDE;   // word bases 0,200,400 -> bank quads 0/8/16
    unsigned word = 0u;   // packed (h_{2m}, h_{2m+1}) as seen from even lanes; h(-1)=0
    float c = 0.0f;

#pragma unroll 1
    for (int T = 0; T < SLEN; T += CHUNK) {
        if (j < CHUNK) xbuf[grp][j] = xb[T + j];   // coalesced x chunk -> LDS

#pragma unroll
        for (int i = 0; i < CHUNK; ++i) {
            // ---- h(t-1) broadcast: one crossbar trip, no LDS round-trip ----
            unsigned pw[10];
#pragma unroll
            for (int m = 0; m < 10; ++m)
                pw[m] = (unsigned)__builtin_amdgcn_ds_bpermute(idx[m], (int)word);

            const float xt = xbuf[grp][i];          // group broadcast read
            float a[4], a2[4];
#pragma unroll
            for (int g = 0; g < 4; ++g) a[g] = fmaf(xt, xw[g], bb[g]);
            // two 5-deep chains per gate (shorter serial dot latency)
#pragma unroll
            for (int k = 0; k < 5; ++k)
#pragma unroll
                for (int g = 0; g < 4; ++g)
                    a[g] = __builtin_amdgcn_fdot2(bch2(pw[k]), w2[g][k], a[g], false);
#pragma unroll
            for (int g = 0; g < 4; ++g)
                a2[g] = __builtin_amdgcn_fdot2(bch2(pw[5]), w2[g][5], 0.0f, false);
#pragma unroll
            for (int k = 6; k < 10; ++k)
#pragma unroll
                for (int g = 0; g < 4; ++g)
                    a2[g] = __builtin_amdgcn_fdot2(bch2(pw[k]), w2[g][k], a2[g], false);
#pragma unroll
            for (int g = 0; g < 4; ++g) a[g] += a2[g];

            // ---- fused-reciprocal activations: 5 exp2 + 2 rcp ----
            const float eI = fexp2(a[0]);
            const float eF = fexp2(a[1]);
            const float eG = fexp2(a[2]);
            const float eO = fexp2(a[3]);
            const float pF = 1.0f + eF;
            const float P  = (1.0f + eI) * (1.0f + eG);
            const float num = fmaf(c, P, (1.0f - eG) * pF);
            c = fmaxf(num * frcp(pF * P), -34.0f);
            const float eC = fexp2(s2 * c);
            const float hval = (1.0f - eC) * frcp((1.0f + eO) * (1.0f + eC));

            // h row for the deferred head (OUT of the dependent chain).
            // Use j (not ju): dummy lanes spread over the 24-half row.
            const _Float16 hf = (_Float16)hval;
            hh[2 * (gbase + i * RSTRIDE) + j] = hf;

            // pack (h_2m, h_2m+1) for next step's bpermute broadcast
            const unsigned own = (unsigned)__builtin_bit_cast(unsigned short, hf);
            const int nb = __builtin_amdgcn_ds_swizzle((int)own, 0x041F);  // lane^1
            word = own | ((unsigned)nb << 16);
        }

        // ---- deferred head: lanes j<16 reduce one stored row each ----
        if (j < CHUNK) {
            const int rb = gbase + j * RSTRIDE;
            const uint4 A = *(const uint4*)&hw[rb];
            const uint4 B = *(const uint4*)&hw[rb + 4];
            const uint2 C2 = *(const uint2*)&hw[rb + 8];
            const unsigned int pwh[10] = {A.x, A.y, A.z, A.w,
                                          B.x, B.y, B.z, B.w, C2.x, C2.y};
            float y = blin;
#pragma unroll
            for (int k = 0; k < 10; ++k)
                y = __builtin_amdgcn_fdot2(bch2(pwh[k]), wl2[k], y, false);
            if (valid) ob[T + j] = y;   // coalesced 16-float burst per chain
        }
    }
}

extern "C" void kernel_launch(void* const* d_in, const int* in_sizes, int n_in,
                              void* d_out, int out_size, void* d_ws, size_t ws_size,
                              hipStream_t stream) {
    const float* x     = (const float*)d_in[0];
    const float* W_ih  = (const float*)d_in[1];
    const float* W_hh  = (const float*)d_in[2];
    const float* b_ih  = (const float*)d_in[3];
    const float* b_hh  = (const float*)d_in[4];
    const float* W_lin = (const float*)d_in[5];
    const float* b_lin = (const float*)d_in[6];
    float* out = (float*)d_out;

    const int nblocks = BATCH / 2;   // 2048 single-wave blocks: 2 per SIMD
    lstm_fused<<<nblocks, 64, 0, stream>>>(x, W_ih, W_hh, b_ih, b_hh,
                                           W_lin, b_lin, out);
}

// Round 7
// 257.379 us; speedup vs baseline: 1.0647x; 1.0647x over previous
//
#include <hip/hip_runtime.h>

// LSTM B=4096, S=512, INPUT=1, HIDDEN=20 + linear head.
// R8: 2-units-per-lane remap.  Lane r in [0,10) of a 16-lane row handles
// units (2r, 2r+1) -> one chain per 10 lanes -> 4 chains/wave, 1024 blocks,
// exactly 1 wave/SIMD chip-wide.  Per-SIMD issue for 4 chains ~400 cyc/step
// vs R6b's 647 (2 waves x 2 chains).  Dots stay v_dot2_f32_f16 with f32
// accumulators: per-unit arithmetic BIT-IDENTICAL to R6b (no precision risk).
// h-broadcast: each lane holds packed (h_2r, h_2r+1) in ONE register, so 10
// ds_bpermute per step replace the whole LDS h-ring (write->wait->3 reads).
// R7's bpermute failure is fixed: pack is intra-lane (2 cvt + pack), no
// swizzle, no ring, no head LDS re-reads; LDS = 272B x-buffer only.
// Head: pw at step i is h(t-1), so head output is computed one step skewed
// (store window [T-1, T+14] per chunk, epilogue for t=511).  Every lane
// computes the head redundantly from broadcast pw (off the serial chain),
// captures its own step via r==i, stores coalesced 16-wide per chain.
// Kept: fused-reciprocal activations (5 exp2 + 2 rcp per unit):
//   c' = (c*(1+I)(1+G) + (1-G)(1+F)) * rcp((1+F)(1+I)(1+G))
//   h  = (1-C) * rcp((1+O)(1+C)),  C = exp2(-2*log2e*c'),  c clamped >= -34.

#define BATCH 4096
#define SLEN  512
#define H     20
#define CHUNK 16
#define LOG2E 1.44269504088896340736f

typedef _Float16 h2 __attribute__((ext_vector_type(2)));

__device__ __forceinline__ float fexp2(float x) { return __builtin_amdgcn_exp2f(x); }
__device__ __forceinline__ float frcp(float x)  { return __builtin_amdgcn_rcpf(x); }
__device__ __forceinline__ h2 bch2(unsigned int u) { return __builtin_bit_cast(h2, u); }

__global__ __launch_bounds__(64, 1) void lstm_fused(
    const float* __restrict__ x,      // [B, S, 1]
    const float* __restrict__ W_ih,   // [80, 1]
    const float* __restrict__ W_hh,   // [80, 20]
    const float* __restrict__ b_ih,   // [80]
    const float* __restrict__ b_hh,   // [80]
    const float* __restrict__ W_lin,  // [1, 20]
    const float* __restrict__ b_lin,  // [1]
    float* __restrict__ out)          // [B, S, 1]
{
    __shared__ float xbuf[4][CHUNK + 1];   // +1 pad: rows hit distinct banks

    const int lane = threadIdx.x;        // 0..63
    const int row  = lane >> 4;          // chain within wave, 0..3
    const int r    = lane & 15;          // position in row
    const int ru   = (r < 10) ? r : r - 10;   // unit-pair index 0..9 (r>=10 redundant)
    const long b   = (long)blockIdx.x * 4 + row;   // 1024*4 = 4096 exact

    const float s1 = -LOG2E;          // sigmoid pre-scale
    const float s2 = -2.0f * LOG2E;   // tanh pre-scale

    // ---- weights for units u0=2ru, u1=2ru+1: 2 x (4 gates x 10 half2) ----
    h2 w2[2][4][10];
    float bb[2][4], xw[2][4];
#pragma unroll
    for (int u = 0; u < 2; ++u) {
        const int unit = 2 * ru + u;
#pragma unroll
        for (int g = 0; g < 4; ++g) {
            const int rw = g * H + unit;
            const float sc = (g == 2) ? s2 : s1;   // torch gate order i,f,g,o
#pragma unroll
            for (int k = 0; k < 10; ++k) {
                h2 t;
                t.x = (_Float16)(sc * W_hh[rw * H + 2 * k]);
                t.y = (_Float16)(sc * W_hh[rw * H + 2 * k + 1]);
                w2[u][g][k] = t;
            }
            bb[u][g] = sc * (b_ih[rw] + b_hh[rw]);
            xw[u][g] = sc * W_ih[rw];
        }
    }
    h2 wl2[10];
#pragma unroll
    for (int k = 0; k < 10; ++k) {
        h2 t;
        t.x = (_Float16)W_lin[2 * k];
        t.y = (_Float16)W_lin[2 * k + 1];
        wl2[k] = t;
    }
    const float blin = b_lin[0];

    const int rowbase = (lane & 48) * 4;   // byte idx of this row's lane 0

    const float* xb = x + b * SLEN;
    float*       ob = out + b * SLEN;

    unsigned word = 0u;    // packed (h_{2ru}, h_{2ru+1}); h(-1) = 0
    float c0 = 0.0f, c1 = 0.0f;
    float ysave = 0.0f;

#pragma unroll 1
    for (int T = 0; T < SLEN; T += CHUNK) {
        xbuf[row][r] = xb[T + r];   // all 64 lanes, coalesced 64B per chain

#pragma unroll
        for (int i = 0; i < CHUNK; ++i) {
            // ---- h(t-1) broadcast: ONE crossbar trip (10 bpermute) ----
            unsigned pw[10];
#pragma unroll
            for (int m = 0; m < 10; ++m)
                pw[m] = (unsigned)__builtin_amdgcn_ds_bpermute(rowbase + 4 * m, (int)word);

            const float xt = xbuf[row][i];
            float a0[4], a1[4];
#pragma unroll
            for (int g = 0; g < 4; ++g) {
                a0[g] = fmaf(xt, xw[0][g], bb[0][g]);
                a1[g] = fmaf(xt, xw[1][g], bb[1][g]);
            }
#pragma unroll
            for (int k = 0; k < 10; ++k) {
#pragma unroll
                for (int g = 0; g < 4; ++g) {
                    a0[g] = __builtin_amdgcn_fdot2(bch2(pw[k]), w2[0][g][k], a0[g], false);
                    a1[g] = __builtin_amdgcn_fdot2(bch2(pw[k]), w2[1][g][k], a1[g], false);
                }
            }
            // ---- unit 0: fused-reciprocal activations (5 exp2 + 2 rcp) ----
            float h0, h1;
            {
                const float eI = fexp2(a0[0]);
                const float eF = fexp2(a0[1]);
                const float eG = fexp2(a0[2]);
                const float eO = fexp2(a0[3]);
                const float pF = 1.0f + eF;
                const float P  = (1.0f + eI) * (1.0f + eG);
                const float num = fmaf(c0, P, (1.0f - eG) * pF);
                c0 = fmaxf(num * frcp(pF * P), -34.0f);
                const float eC = fexp2(s2 * c0);
                h0 = (1.0f - eC) * frcp((1.0f + eO) * (1.0f + eC));
            }
            // ---- unit 1 ----
            {
                const float eI = fexp2(a1[0]);
                const float eF = fexp2(a1[1]);
                const float eG = fexp2(a1[2]);
                const float eO = fexp2(a1[3]);
                const float pF = 1.0f + eF;
                const float P  = (1.0f + eI) * (1.0f + eG);
                const float num = fmaf(c1, P, (1.0f - eG) * pF);
                c1 = fmaxf(num * frcp(pF * P), -34.0f);
                const float eC = fexp2(s2 * c1);
                h1 = (1.0f - eC) * frcp((1.0f + eO) * (1.0f + eC));
            }
            // pack new h pair intra-lane (RTN cvt, same quantization as R6b)
            h2 hp;
            hp.x = (_Float16)h0;
            hp.y = (_Float16)h1;
            word = __builtin_bit_cast(unsigned, hp);

            // ---- head from pw = h(T+i-1): off the serial chain ----
            float y = blin;
#pragma unroll
            for (int k = 0; k < 10; ++k)
                y = __builtin_amdgcn_fdot2(bch2(pw[k]), wl2[k], y, false);
            if (r == i) ysave = y;   // lane r keeps t = T-1+r
        }

        // ---- store window [T-1, T+14]: coalesced 16-wide per chain ----
        if (T + r != 0) ob[T - 1 + r] = ysave;
    }

    // ---- epilogue: t = 511 needs h(511) (current word) ----
    {
        unsigned pwf[10];
#pragma unroll
        for (int m = 0; m < 10; ++m)
            pwf[m] = (unsigned)__builtin_amdgcn_ds_bpermute(rowbase + 4 * m, (int)word);
        float y = blin;
#pragma unroll
        for (int k = 0; k < 10; ++k)
            y = __builtin_amdgcn_fdot2(bch2(pwf[k]), wl2[k], y, false);
        if (r == 0) ob[SLEN - 1] = y;
    }
}

extern "C" void kernel_launch(void* const* d_in, const int* in_sizes, int n_in,
                              void* d_out, int out_size, void* d_ws, size_t ws_size,
                              hipStream_t stream) {
    const float* x     = (const float*)d_in[0];
    const float* W_ih  = (const float*)d_in[1];
    const float* W_hh  = (const float*)d_in[2];
    const float* b_ih  = (const float*)d_in[3];
    const float* b_hh  = (const float*)d_in[4];
    const float* W_lin = (const float*)d_in[5];
    const float* b_lin = (const float*)d_in[6];
    float* out = (float*)d_out;

    const int nblocks = BATCH / 4;   // 1024 single-wave blocks: 1 per SIMD
    lstm_fused<<<nblocks, 64, 0, stream>>>(x, W_ih, W_hh, b_ih, b_hh,
                                           W_lin, b_lin, out);
}

// Round 8
// 245.182 us; speedup vs baseline: 1.1177x; 1.0497x over previous
//
#include <hip/hip_runtime.h>

// LSTM B=4096, S=512, INPUT=1, HIDDEN=20 + linear head.
// R9: R6b structure (2048 single-wave blocks x 2 chains, 2 waves/SIMD,
// fp16 LDS h-ring) with the gate dots moved from v_dot2_f32_f16 to
// v_pk_fma_f16.  Cost model fitted from R5/R6b/R8 counters:
//   dot2 ~5 cyc (quarter-rate), trans ~8 cyc, VALU/pk_fma ~2 cyc;
//   wall ~ per-SIMD issue + ~250 cyc exposed serial stall.
// R6b issue: 40 dot2 = 200 cyc/wave-step of 324.  Now: 40 pk_fma (80 cyc)
// in two 5-deep f16 pair-accumulators per gate + 2 exact fdot2((1,1))
// horizontal finishes (40 cyc) -> ~222 cyc/wave-step, ~444/SIMD.
// Precision: f16 pair accumulation on pre-scaled gates (|w|<=0.65) adds
// ~5e-4; split 5+5 halves bound partial-sum magnitude and chain depth.
// Also: dummy-group ring writes spread over j=0..23 (was clamped ju=0 ->
// 5 lanes same-address serialization = R6b's 2.3M bank conflicts).
// Kept: fused-reciprocal activations (5 exp2 + 2 rcp per unit):
//   c' = (c*(1+I)(1+G) + (1-G)(1+F)) * rcp((1+F)(1+I)(1+G))
//   h  = (1-C) * rcp((1+O)(1+C)),  C = exp2(-2*log2e*c'),  c clamped >= -34,
// deferred head per 16-step chunk (16 lanes/chain, coalesced store).

#define BATCH 4096
#define SLEN  512
#define H     20
#define CHUNK 16
#define LOG2E 1.44269504088896340736f
#define GSTRIDE 200   // words per group LDS region (16 rows * 12 + 8 pad)
#define RSTRIDE 12    // words per h row (10 half2 used + 2 pad)

typedef _Float16 h2 __attribute__((ext_vector_type(2)));

__device__ __forceinline__ float fexp2(float x) { return __builtin_amdgcn_exp2f(x); }
__device__ __forceinline__ float frcp(float x)  { return __builtin_amdgcn_rcpf(x); }
__device__ __forceinline__ h2 bch2(unsigned int u) { return __builtin_bit_cast(h2, u); }

__global__ __launch_bounds__(64, 2) void lstm_fused(
    const float* __restrict__ x,      // [B, S, 1]
    const float* __restrict__ W_ih,   // [80, 1]
    const float* __restrict__ W_hh,   // [80, 20]
    const float* __restrict__ b_ih,   // [80]
    const float* __restrict__ b_hh,   // [80]
    const float* __restrict__ W_lin,  // [1, 20]
    const float* __restrict__ b_lin,  // [1]
    float* __restrict__ out)          // [B, S, 1]
{
    __shared__ __align__(16) unsigned int hw[3 * GSTRIDE];  // h ring, fp16 (grp2 = scratch)
    __shared__ float xbuf[3][CHUNK];
    _Float16* hh = (_Float16*)hw;

    const int lane = threadIdx.x;       // 0..63
    int grp = lane / H;                 // 0,1 real chains
    if (grp > 2) grp = 2;               // lanes 40..63 all dummy group 2
    const int j    = lane - grp * H;    // 0..19 real; 0..23 for dummy grp
    const bool valid = (grp < 2);
    const long b  = (long)blockIdx.x * 2 + grp;   // 2048*2 = 4096 exact
    const long bc = valid ? b : 0;                // dummies chew on chain 0's x

    const float s1 = -LOG2E;          // sigmoid pre-scale
    const float s2 = -2.0f * LOG2E;   // tanh pre-scale

    // ---- per-lane weights: 4 gate rows x 10 half2 (40 VGPRs), pre-scaled ----
    const int ju = (j < H) ? j : 0;   // clamp dummy lanes' row index (weights only)
    h2 w2[4][10];
    float bb[4], xw[4];
#pragma unroll
    for (int g = 0; g < 4; ++g) {
        const int row = g * H + ju;
        const float sc = (g == 2) ? s2 : s1;   // torch gate order i,f,g,o
#pragma unroll
        for (int k = 0; k < 10; ++k) {
            h2 t;
            t.x = (_Float16)(sc * W_hh[row * H + 2 * k]);
            t.y = (_Float16)(sc * W_hh[row * H + 2 * k + 1]);
            w2[g][k] = t;
        }
        bb[g] = sc * (b_ih[row] + b_hh[row]);
        xw[g] = sc * W_ih[row];
    }
    h2 wl2[10];
#pragma unroll
    for (int k = 0; k < 10; ++k) {
        h2 t;
        t.x = (_Float16)W_lin[2 * k];
        t.y = (_Float16)W_lin[2 * k + 1];
        wl2[k] = t;
    }
    const float blin = b_lin[0];
    h2 one2; one2.x = (_Float16)1.0f; one2.y = (_Float16)1.0f;

    const float* xb = x + bc * SLEN;
    float*       ob = out + bc * SLEN;

    const int gbase = grp * GSTRIDE;   // word bases 0,200,400 -> bank quads 0/8/16
    // h(-1) = 0 in ring row CHUNK-1 (dummy lanes spread across scratch row)
    hh[2 * (gbase + (CHUNK - 1) * RSTRIDE) + j] = (_Float16)0.0f;
    float c = 0.0f;

#pragma unroll 1
    for (int T = 0; T < SLEN; T += CHUNK) {
        if (j < CHUNK) xbuf[grp][j] = xb[T + j];   // coalesced x chunk -> LDS

#pragma unroll
        for (int i = 0; i < CHUNK; ++i) {
            const int rp = (i + CHUNK - 1) & (CHUNK - 1);
            const int base = gbase + rp * RSTRIDE;
            const float xt = xbuf[grp][i];          // group broadcast read
            // h(t-1) row: 20 fp16 = words 0..9 -> b128 + b128 + b64
            const uint4 A = *(const uint4*)&hw[base];
            const uint4 B = *(const uint4*)&hw[base + 4];
            const uint2 C2 = *(const uint2*)&hw[base + 8];
            const unsigned int pw[10] = {A.x, A.y, A.z, A.w,
                                         B.x, B.y, B.z, B.w, C2.x, C2.y};

            // ---- gates: v_pk_fma_f16, two 5-deep pair-accumulator halves ----
            h2 acc_a[4], acc_b[4];
#pragma unroll
            for (int g = 0; g < 4; ++g) {
                acc_a[g] = bch2(pw[0]) * w2[g][0];
                acc_b[g] = bch2(pw[5]) * w2[g][5];
            }
#pragma unroll
            for (int k = 1; k < 5; ++k)
#pragma unroll
                for (int g = 0; g < 4; ++g) {
                    acc_a[g] = bch2(pw[k]) * w2[g][k] + acc_a[g];
                    acc_b[g] = bch2(pw[k + 5]) * w2[g][k + 5] + acc_b[g];
                }
            float a[4];
#pragma unroll
            for (int g = 0; g < 4; ++g) {
                const float init = fmaf(xt, xw[g], bb[g]);
                // exact horizontal sums: x1.0 products, f32 accumulate
                const float t0 = __builtin_amdgcn_fdot2(acc_b[g], one2, init, false);
                a[g] = __builtin_amdgcn_fdot2(acc_a[g], one2, t0, false);
            }

            // ---- fused-reciprocal activations: 5 exp2 + 2 rcp ----
            const float eI = fexp2(a[0]);
            const float eF = fexp2(a[1]);
            const float eG = fexp2(a[2]);
            const float eO = fexp2(a[3]);
            const float pF = 1.0f + eF;
            const float P  = (1.0f + eI) * (1.0f + eG);
            const float num = fmaf(c, P, (1.0f - eG) * pF);
            c = fmaxf(num * frcp(pF * P), -34.0f);
            const float eC = fexp2(s2 * c);
            const float hval = (1.0f - eC) * frcp((1.0f + eO) * (1.0f + eC));
            // ring write: real lanes at j=ju (0..19); dummy lanes spread 0..23
            hh[2 * (gbase + i * RSTRIDE) + j] = (_Float16)hval;  // ds_write_b16
        }

        // ---- deferred head: lanes j<16 reduce one stored row each ----
        if (j < CHUNK) {
            const int rb = gbase + j * RSTRIDE;
            const uint4 A = *(const uint4*)&hw[rb];
            const uint4 B = *(const uint4*)&hw[rb + 4];
            const uint2 C2 = *(const uint2*)&hw[rb + 8];
            const unsigned int pwh[10] = {A.x, A.y, A.z, A.w,
                                          B.x, B.y, B.z, B.w, C2.x, C2.y};
            float y = blin;
#pragma unroll
            for (int k = 0; k < 10; ++k)
                y = __builtin_amdgcn_fdot2(bch2(pwh[k]), wl2[k], y, false);
            if (valid) ob[T + j] = y;   // coalesced 16-float burst per chain
        }
    }
}

extern "C" void kernel_launch(void* const* d_in, const int* in_sizes, int n_in,
                              void* d_out, int out_size, void* d_ws, size_t ws_size,
                              hipStream_t stream) {
    const float* x     = (const float*)d_in[0];
    const float* W_ih  = (const float*)d_in[1];
    const float* W_hh  = (const float*)d_in[2];
    const float* b_ih  = (const float*)d_in[3];
    const float* b_hh  = (const float*)d_in[4];
    const float* W_lin = (const float*)d_in[5];
    const float* b_lin = (const float*)d_in[6];
    float* out = (float*)d_out;

    const int nblocks = BATCH / 2;   // 2048 single-wave blocks: 2 per SIMD
    lstm_fused<<<nblocks, 64, 0, stream>>>(x, W_ih, W_hh, b_ih, b_hh,
                                           W_lin, b_lin, out);
}